// Round 3
// baseline (1428.067 us; speedup 1.0000x reference)
//
#include <hip/hip_runtime.h>
#include <math.h>

// ---------------------------------------------------------------------------
// Polytope projection via dual PGD, restructured:
//   H = A A^T; eta = 1.8/lambda_max(H) (power iter); M = I - eta*H (sym)
//   r = eta*(x A^T - b); lam <- relu(lam M + r) x29 (lam0 = relu(r));
//   out = x - lam A
// All heavy GEMMs: fp16x2 split (Ootomo, v = hi + lo/2048, 3 MFMAs/product),
// 128x128 block tile, 4 waves x (64x64), mfma_f32_32x32x16_f16, BK=32,
// double-buffered LDS with early-issued global_load_lds, packed h|l rows
// with XOR-8 swizzle (pre-swizzled source + swizzled ds_read), XCD swizzle.
// ---------------------------------------------------------------------------

typedef _Float16 f16x8 __attribute__((ext_vector_type(8)));
typedef _Float16 f16x4 __attribute__((ext_vector_type(4)));
typedef float f32x16 __attribute__((ext_vector_type(16)));

#define GLD16(G, L)                                                          \
  __builtin_amdgcn_global_load_lds(                                          \
      (const __attribute__((address_space(1))) void*)(const void*)(G),       \
      (__attribute__((address_space(3))) void*)(void*)(L), 16, 0, 0)

// ---------------- elementwise split kernels ----------------

// n/1024 blocks, 256 thr: f32 -> (hi, lo*2048) f16 pair
__global__ __launch_bounds__(256) void k_split(const float* __restrict__ A,
                                               _Float16* __restrict__ Ah,
                                               _Float16* __restrict__ Al) {
    size_t i4 = ((size_t)blockIdx.x * 256 + threadIdx.x) * 4;
    float4 v = *(const float4*)(A + i4);
    float va[4] = {v.x, v.y, v.z, v.w};
    f16x4 hh, ll;
#pragma unroll
    for (int e = 0; e < 4; ++e) {
        _Float16 h = (_Float16)va[e];
        hh[e] = h;
        ll[e] = (_Float16)((va[e] - (float)h) * 2048.f);
    }
    *(f16x4*)(Ah + i4) = hh;
    *(f16x4*)(Al + i4) = ll;
}

// M = I - eta*H, split (m=1024 hardcoded row length)
__global__ __launch_bounds__(256) void k_makeM(const float* __restrict__ H,
                                               const float* __restrict__ eta_p,
                                               _Float16* __restrict__ Mh,
                                               _Float16* __restrict__ Ml) {
    float eta = eta_p[0];
    size_t i4 = ((size_t)blockIdx.x * 256 + threadIdx.x) * 4;
    float4 v = *(const float4*)(H + i4);
    float va[4] = {v.x, v.y, v.z, v.w};
    int row = (int)(i4 >> 10);
    int col0 = (int)(i4 & 1023);
    f16x4 hh, ll;
#pragma unroll
    for (int e = 0; e < 4; ++e) {
        float mv = ((col0 + e) == row ? 1.f : 0.f) - eta * va[e];
        _Float16 h = (_Float16)mv;
        hh[e] = h;
        ll[e] = (_Float16)((mv - (float)h) * 2048.f);
    }
    *(f16x4*)(Mh + i4) = hh;
    *(f16x4*)(Ml + i4) = ll;
}

// A [1024,1024] -> A^T split via 32x32 LDS tiles
__global__ __launch_bounds__(256) void k_tsplit(const float* __restrict__ A,
                                                _Float16* __restrict__ Th,
                                                _Float16* __restrict__ Tl) {
    __shared__ float ts[32][33];
    int i0 = blockIdx.x * 32, j0 = blockIdx.y * 32;
    int tr = threadIdx.x >> 3, tc4 = (threadIdx.x & 7) * 4;
    float4 v = *(const float4*)(A + (size_t)(i0 + tr) * 1024 + j0 + tc4);
    ts[tr][tc4] = v.x; ts[tr][tc4 + 1] = v.y;
    ts[tr][tc4 + 2] = v.z; ts[tr][tc4 + 3] = v.w;
    __syncthreads();
    f16x4 hh, ll;
#pragma unroll
    for (int e = 0; e < 4; ++e) {
        float x = ts[tc4 + e][tr];
        _Float16 h = (_Float16)x;
        hh[e] = h;
        ll[e] = (_Float16)((x - (float)h) * 2048.f);
    }
    *(f16x4*)(Th + (size_t)(j0 + tr) * 1024 + i0 + tc4) = hh;
    *(f16x4*)(Tl + (size_t)(j0 + tr) * 1024 + i0 + tc4) = ll;
}

// ---------------- power iteration on H ----------------

// u0 = A * ones / sqrt(1024)
__global__ __launch_bounds__(256) void k_u0(const float* __restrict__ A,
                                            float* __restrict__ u) {
    int r = blockIdx.x * 16 + (threadIdx.x >> 4);
    int gq = threadIdx.x & 15;
    const float* ar = A + (size_t)r * 1024;
    float s = 0.f;
    for (int c = gq * 4; c < 1024; c += 64) {
        float4 v = *(const float4*)(ar + c);
        s += v.x + v.y + v.z + v.w;
    }
    s += __shfl_xor(s, 1, 16); s += __shfl_xor(s, 2, 16);
    s += __shfl_xor(s, 4, 16); s += __shfl_xor(s, 8, 16);
    if (gq == 0) u[r] = s * 0.03125f;
}

// wout = H * (win / (||win|| + 1e-12));  grid 256, 4 rows/block (1 wave/row)
__global__ __launch_bounds__(256) void k_pmv(const float* __restrict__ H,
                                             const float* __restrict__ win,
                                             float* __restrict__ wout) {
    __shared__ float red[256];
    int t = threadIdx.x;
    float4 v = *(const float4*)(win + t * 4);
    red[t] = v.x * v.x + v.y * v.y + v.z * v.z + v.w * v.w;
    __syncthreads();
    for (int o = 128; o > 0; o >>= 1) {
        if (t < o) red[t] += red[t + o];
        __syncthreads();
    }
    float inv = 1.f / (sqrtf(red[0]) + 1e-12f);
    int row = blockIdx.x * 4 + (t >> 6);
    int lane = t & 63;
    const float* hr = H + (size_t)row * 1024;
    float s = 0.f;
#pragma unroll
    for (int seg = 0; seg < 4; ++seg) {
        float4 hv = *(const float4*)(hr + seg * 256 + lane * 4);
        float4 uv = *(const float4*)(win + seg * 256 + lane * 4);
        s += hv.x * uv.x + hv.y * uv.y + hv.z * uv.z + hv.w * uv.w;
    }
#pragma unroll
    for (int k = 1; k < 64; k <<= 1) s += __shfl_xor(s, k);
    if (lane == 0) wout[row] = s * inv;
}

// eta = 1.8*(w9.w10) / ((||w9||+1e-12) * (w10.w10))
__global__ __launch_bounds__(256) void k_eta3(const float* __restrict__ w9,
                                              const float* __restrict__ w10,
                                              float* __restrict__ eta) {
    __shared__ float r99[256], r910[256], r1010[256];
    int t = threadIdx.x;
    float4 a = *(const float4*)(w9 + t * 4);
    float4 b = *(const float4*)(w10 + t * 4);
    r99[t] = a.x * a.x + a.y * a.y + a.z * a.z + a.w * a.w;
    r910[t] = a.x * b.x + a.y * b.y + a.z * b.z + a.w * b.w;
    r1010[t] = b.x * b.x + b.y * b.y + b.z * b.z + b.w * b.w;
    __syncthreads();
    for (int o = 128; o > 0; o >>= 1) {
        if (t < o) {
            r99[t] += r99[t + o];
            r910[t] += r910[t + o];
            r1010[t] += r1010[t + o];
        }
        __syncthreads();
    }
    if (t == 0)
        eta[0] = 1.8f * r910[0] / ((sqrtf(r99[0]) + 1e-12f) * r1010[0]);
}

// ---------------- fp16x2 split NT MFMA GEMM (32x32x16) ----------------
// C[i][j] = sum_k Aop[i][k]*Bop[j][k]. Block 128x128, 4 waves (2x2), each
// wave 64x64 (2x2 frags of 32x32). BK=32, double-buffered LDS (64KB).
// LDS tile row = 8 x 16B slots: slots 0-3 = hi k-chunks, 4-7 = lo k-chunks,
// physical slot = logical ^ (row&7) (involution; staged via swizzled source).
// EPI 0: fout = acc                          (H)
// EPI 1: rv = eta*(acc - b[j]) -> fout; lam0 = relu(rv) split
// EPI 2: lam = relu(acc + raux) split        (iteration)
// EPI 3: fout = raux - acc                   (final out; raux = x)

template <int EPI>
__global__ __launch_bounds__(256, 1) void k_mm2(
    const _Float16* __restrict__ Agh, const _Float16* __restrict__ Agl,
    const _Float16* __restrict__ Bgh, const _Float16* __restrict__ Bgl,
    int Kd, int Nd,
    const float* __restrict__ eta_p, const float* __restrict__ bvec,
    const float* __restrict__ raux, float* __restrict__ fout,
    _Float16* __restrict__ lamh, _Float16* __restrict__ laml) {
    __shared__ __align__(16) char lds[65536];

    const int t = threadIdx.x;
    const int wid = t >> 6, lane = t & 63;
    const int wr = wid >> 1, wc = wid & 1;
    const int l31 = lane & 31, g2 = lane >> 5;

    // bijective XCD swizzle (nwg % 8 == 0 for all our grids)
    const int nwg = gridDim.x * gridDim.y;
    const int id = blockIdx.x + blockIdx.y * gridDim.x;
    const int id2 = (id & 7) * (nwg >> 3) + (id >> 3);
    const int rowBase = (id2 % gridDim.x) * 128;
    const int colBase = (id2 / gridDim.x) * 128;

    // staging source (pre-swizzled so linear LDS dest holds swizzled layout)
    const int srow = t >> 3;                 // 0..31: row within 32-row group
    const int slot = t & 7;                  // 16B slot within row
    const int jch = slot ^ (srow & 7);       // logical chunk at this slot
    const int kch = (jch & 3) * 8;           // k element offset (per h/l half)
    const _Float16* srcA =
        (jch >= 4 ? Agl : Agh) + (size_t)(rowBase + srow) * Kd + kch;
    const _Float16* srcB =
        (jch >= 4 ? Bgl : Bgh) + (size_t)(colBase + srow) * Kd + kch;
    const size_t qStep = (size_t)32 * Kd;

#define STAGE(P, KO)                                                         \
    {                                                                        \
        _Pragma("unroll") for (int q = 0; q < 4; ++q)                        \
            GLD16(srcA + (KO) + q * qStep,                                   \
                  lds + (P)*32768 + q * 4096 + wid * 1024);                  \
        _Pragma("unroll") for (int q = 0; q < 4; ++q)                        \
            GLD16(srcB + (KO) + q * qStep,                                   \
                  lds + (P)*32768 + 16384 + q * 4096 + wid * 1024);          \
    }

    f32x16 acch[2][2], accm[2][2];
#pragma unroll
    for (int m2 = 0; m2 < 2; ++m2)
#pragma unroll
        for (int n2 = 0; n2 < 2; ++n2) {
            acch[m2][n2] = (f32x16)0.f;
            accm[m2][n2] = (f32x16)0.f;
        }

    STAGE(0, 0);
    __syncthreads();

    const int NS = Kd >> 5;
    for (int ks = 0; ks < NS; ++ks) {
        const int p = ks & 1;
        if (ks + 1 < NS) STAGE(p ^ 1, (ks + 1) << 5);

        const char* base = lds + p * 32768;
#pragma unroll
        for (int ksub = 0; ksub < 2; ++ksub) {
            const int j = ksub * 2 + g2;
            f16x8 ah[2], al[2], bh[2], bl[2];
#pragma unroll
            for (int m2 = 0; m2 < 2; ++m2) {
                int row = wr * 64 + m2 * 32 + l31;
                const char* rp = base + row * 128;
                ah[m2] = *(const f16x8*)(rp + ((j ^ (row & 7)) << 4));
                al[m2] = *(const f16x8*)(rp + (((j + 4) ^ (row & 7)) << 4));
            }
#pragma unroll
            for (int n2 = 0; n2 < 2; ++n2) {
                int row = wc * 64 + n2 * 32 + l31;
                const char* rp = base + 16384 + row * 128;
                bh[n2] = *(const f16x8*)(rp + ((j ^ (row & 7)) << 4));
                bl[n2] = *(const f16x8*)(rp + (((j + 4) ^ (row & 7)) << 4));
            }
#pragma unroll
            for (int m2 = 0; m2 < 2; ++m2)
#pragma unroll
                for (int n2 = 0; n2 < 2; ++n2) {
                    acch[m2][n2] = __builtin_amdgcn_mfma_f32_32x32x16_f16(
                        ah[m2], bh[n2], acch[m2][n2], 0, 0, 0);
                    accm[m2][n2] = __builtin_amdgcn_mfma_f32_32x32x16_f16(
                        ah[m2], bl[n2], accm[m2][n2], 0, 0, 0);
                    accm[m2][n2] = __builtin_amdgcn_mfma_f32_32x32x16_f16(
                        al[m2], bh[n2], accm[m2][n2], 0, 0, 0);
                }
        }
        if (ks + 1 < NS) __syncthreads();
    }
#undef STAGE

    // ---- epilogue; C layout: col = lane&31, row = (reg&3)+8*(reg>>2)+4*g2
    float etav = (EPI == 1) ? eta_p[0] : 0.f;
#pragma unroll
    for (int m2 = 0; m2 < 2; ++m2)
#pragma unroll
        for (int n2 = 0; n2 < 2; ++n2) {
            const int col = colBase + wc * 64 + n2 * 32 + l31;
#pragma unroll
            for (int reg = 0; reg < 16; ++reg) {
                const int row = rowBase + wr * 64 + m2 * 32 + (reg & 3) +
                                ((reg >> 2) << 3) + (g2 << 2);
                const size_t idx = (size_t)row * Nd + col;
                float val =
                    acch[m2][n2][reg] + accm[m2][n2][reg] * 4.8828125e-4f;
                if (EPI == 0) {
                    fout[idx] = val;
                } else if (EPI == 1) {
                    float rv = etav * (val - bvec[col]);
                    fout[idx] = rv;
                    float lv = fmaxf(rv, 0.f);
                    _Float16 h = (_Float16)lv;
                    lamh[idx] = h;
                    laml[idx] = (_Float16)((lv - (float)h) * 2048.f);
                } else if (EPI == 2) {
                    float lv = fmaxf(val + raux[idx], 0.f);
                    _Float16 h = (_Float16)lv;
                    lamh[idx] = h;
                    laml[idx] = (_Float16)((lv - (float)h) * 2048.f);
                } else {
                    fout[idx] = raux[idx] - val;
                }
            }
        }
}

// ---------------------------------------------------------------------------

extern "C" void kernel_launch(void* const* d_in, const int* in_sizes, int n_in,
                              void* d_out, int out_size, void* d_ws, size_t ws_size,
                              hipStream_t stream) {
    const float* x = (const float*)d_in[0];  // [B, d] = [4096, 1024]
    const float* A = (const float*)d_in[1];  // [m, d] = [1024, 1024]
    const float* b = (const float*)d_in[2];  // [m]

    const int m = in_sizes[2];           // 1024
    const int dd = in_sizes[1] / m;      // 1024
    const int Bn = in_sizes[0] / dd;     // 4096
    float* out = (float*)d_out;

    // workspace layout (<= 60 MB + 16 KB; x-split region is reused as l1,
    // H region is reused for A^T split after makeM)
    const size_t MB = 1u << 20;
    char* w8 = (char*)d_ws;
    float* eta = (float*)w8;                       // 256 B
    float* wA = (float*)(w8 + 256);                // 4 KB
    float* wB = (float*)(w8 + 256 + 4096);         // 4 KB
    char* base = w8 + 16384;
    float* H = (float*)base;                       // 4 MB (later: AT split)
    _Float16* ATh = (_Float16*)base;               //   2 MB (aliases H)
    _Float16* ATl = (_Float16*)(base + 2 * MB);    //   2 MB (aliases H)
    _Float16* Mh = (_Float16*)(base + 4 * MB);     // 2 MB
    _Float16* Ml = (_Float16*)(base + 6 * MB);     // 2 MB
    _Float16* Ah = (_Float16*)(base + 8 * MB);     // 2 MB
    _Float16* Al = (_Float16*)(base + 10 * MB);    // 2 MB
    _Float16* xh = (_Float16*)(base + 12 * MB);    // 8 MB (later: l1h)
    _Float16* xl = (_Float16*)(base + 20 * MB);    // 8 MB (later: l1l)
    float* r = (float*)(base + 28 * MB);           // 16 MB
    _Float16* l0h = (_Float16*)(base + 44 * MB);   // 8 MB
    _Float16* l0l = (_Float16*)(base + 52 * MB);   // 8 MB
    _Float16* l1h = xh;
    _Float16* l1l = xl;

    // ---- split A and x ----
    k_split<<<(m * dd) / 1024, 256, 0, stream>>>(A, Ah, Al);
    k_split<<<(Bn * dd) / 1024, 256, 0, stream>>>(x, xh, xl);

    // ---- H = A A^T ----
    k_mm2<0><<<dim3(m / 128, m / 128), 256, 0, stream>>>(
        Ah, Al, Ah, Al, dd, m, nullptr, nullptr, nullptr, H, nullptr, nullptr);

    // ---- power iteration: eta = 1.8/lambda_max(H) ----
    k_u0<<<m / 16, 256, 0, stream>>>(A, wA);
    for (int it = 0; it < 5; ++it) {
        k_pmv<<<m / 4, 256, 0, stream>>>(H, wA, wB);
        k_pmv<<<m / 4, 256, 0, stream>>>(H, wB, wA);
    }
    // w9 in wB, w10 in wA
    k_eta3<<<1, 256, 0, stream>>>(wB, wA, eta);

    // ---- M = I - eta*H (split f16) ----
    k_makeM<<<(m * m) / 1024, 256, 0, stream>>>(H, eta, Mh, Ml);

    // ---- r = eta*(x A^T - b); lam0 = relu(r) split ----
    k_mm2<1><<<dim3(Bn / 128, m / 128), 256, 0, stream>>>(
        xh, xl, Ah, Al, dd, m, eta, b, nullptr, r, l0h, l0l);

    // ---- 29 iterations: lam <- relu(lam M + r) ----
    const _Float16 *pih = l0h, *pil = l0l;
    _Float16 *poh = l1h, *pol = l1l;
    for (int it = 0; it < 29; ++it) {
        k_mm2<2><<<dim3(Bn / 128, m / 128), 256, 0, stream>>>(
            pih, pil, Mh, Ml, m, m, nullptr, nullptr, r, nullptr, poh, pol);
        const _Float16* th = pih;
        const _Float16* tl = pil;
        pih = poh; pil = pol;
        poh = (_Float16*)th; pol = (_Float16*)tl;
    }
    // 29 steps: final lam in l1 (x-split no longer needed)

    // ---- A^T split into old H region; out = x - lam A ----
    k_tsplit<<<dim3(m / 32, dd / 32), 256, 0, stream>>>(A, ATh, ATl);
    k_mm2<3><<<dim3(Bn / 128, dd / 128), 256, 0, stream>>>(
        pih, pil, ATh, ATl, m, dd, nullptr, nullptr, x, out, nullptr, nullptr);
}

// Round 4
// 1121.166 us; speedup vs baseline: 1.2737x; 1.2737x over previous
//
#include <hip/hip_runtime.h>
#include <math.h>

// ---------------------------------------------------------------------------
// Polytope projection via dual PGD, restructured:
//   H = A A^T; eta = 1.8/lambda_max(H) (power iter); M = I - eta*H (sym)
//   r = eta*(x A^T - b); lam <- relu(lam M + r) x29 (lam0 = relu(r));
//   out = x - lam A
// Heavy GEMMs: fp16x2 split (Ootomo, v = hi + lo/2048, 3 MFMAs/product),
// 128x128 block tile, 4 waves x (64x64), mfma_f32_32x32x16_f16, BK=32,
// double-buffered LDS, RAW s_barrier + counted s_waitcnt vmcnt(8) so the
// next tile's global_load_lds stay in flight across the barrier (T3/T4),
// 2 blocks/CU, chunked bijective XCD swizzle.
// ---------------------------------------------------------------------------

typedef _Float16 f16x8 __attribute__((ext_vector_type(8)));
typedef _Float16 f16x4 __attribute__((ext_vector_type(4)));
typedef float f32x16 __attribute__((ext_vector_type(16)));

#define GLD16(G, L)                                                          \
  __builtin_amdgcn_global_load_lds(                                          \
      (const __attribute__((address_space(1))) void*)(const void*)(G),       \
      (__attribute__((address_space(3))) void*)(void*)(L), 16, 0, 0)

// ---------------- elementwise split kernels ----------------

// n/1024 blocks, 256 thr: f32 -> (hi, lo*2048) f16 pair
__global__ __launch_bounds__(256) void k_split(const float* __restrict__ A,
                                               _Float16* __restrict__ Ah,
                                               _Float16* __restrict__ Al) {
    size_t i4 = ((size_t)blockIdx.x * 256 + threadIdx.x) * 4;
    float4 v = *(const float4*)(A + i4);
    float va[4] = {v.x, v.y, v.z, v.w};
    f16x4 hh, ll;
#pragma unroll
    for (int e = 0; e < 4; ++e) {
        _Float16 h = (_Float16)va[e];
        hh[e] = h;
        ll[e] = (_Float16)((va[e] - (float)h) * 2048.f);
    }
    *(f16x4*)(Ah + i4) = hh;
    *(f16x4*)(Al + i4) = ll;
}

// M = I - eta*H, split (m=1024 hardcoded row length)
__global__ __launch_bounds__(256) void k_makeM(const float* __restrict__ H,
                                               const float* __restrict__ eta_p,
                                               _Float16* __restrict__ Mh,
                                               _Float16* __restrict__ Ml) {
    float eta = eta_p[0];
    size_t i4 = ((size_t)blockIdx.x * 256 + threadIdx.x) * 4;
    float4 v = *(const float4*)(H + i4);
    float va[4] = {v.x, v.y, v.z, v.w};
    int row = (int)(i4 >> 10);
    int col0 = (int)(i4 & 1023);
    f16x4 hh, ll;
#pragma unroll
    for (int e = 0; e < 4; ++e) {
        float mv = ((col0 + e) == row ? 1.f : 0.f) - eta * va[e];
        _Float16 h = (_Float16)mv;
        hh[e] = h;
        ll[e] = (_Float16)((mv - (float)h) * 2048.f);
    }
    *(f16x4*)(Mh + i4) = hh;
    *(f16x4*)(Ml + i4) = ll;
}

// A [1024,1024] -> A^T split via 32x32 LDS tiles
__global__ __launch_bounds__(256) void k_tsplit(const float* __restrict__ A,
                                                _Float16* __restrict__ Th,
                                                _Float16* __restrict__ Tl) {
    __shared__ float ts[32][33];
    int i0 = blockIdx.x * 32, j0 = blockIdx.y * 32;
    int tr = threadIdx.x >> 3, tc4 = (threadIdx.x & 7) * 4;
    float4 v = *(const float4*)(A + (size_t)(i0 + tr) * 1024 + j0 + tc4);
    ts[tr][tc4] = v.x; ts[tr][tc4 + 1] = v.y;
    ts[tr][tc4 + 2] = v.z; ts[tr][tc4 + 3] = v.w;
    __syncthreads();
    f16x4 hh, ll;
#pragma unroll
    for (int e = 0; e < 4; ++e) {
        float x = ts[tc4 + e][tr];
        _Float16 h = (_Float16)x;
        hh[e] = h;
        ll[e] = (_Float16)((x - (float)h) * 2048.f);
    }
    *(f16x4*)(Th + (size_t)(j0 + tr) * 1024 + i0 + tc4) = hh;
    *(f16x4*)(Tl + (size_t)(j0 + tr) * 1024 + i0 + tc4) = ll;
}

// ---------------- power iteration on H ----------------

// u0 = A * ones / sqrt(1024)
__global__ __launch_bounds__(256) void k_u0(const float* __restrict__ A,
                                            float* __restrict__ u) {
    int r = blockIdx.x * 16 + (threadIdx.x >> 4);
    int gq = threadIdx.x & 15;
    const float* ar = A + (size_t)r * 1024;
    float s = 0.f;
    for (int c = gq * 4; c < 1024; c += 64) {
        float4 v = *(const float4*)(ar + c);
        s += v.x + v.y + v.z + v.w;
    }
    s += __shfl_xor(s, 1, 16); s += __shfl_xor(s, 2, 16);
    s += __shfl_xor(s, 4, 16); s += __shfl_xor(s, 8, 16);
    if (gq == 0) u[r] = s * 0.03125f;
}

// wout = H * (win / (||win|| + 1e-12));  grid 256, 4 rows/block (1 wave/row)
__global__ __launch_bounds__(256) void k_pmv(const float* __restrict__ H,
                                             const float* __restrict__ win,
                                             float* __restrict__ wout) {
    __shared__ float red[256];
    int t = threadIdx.x;
    float4 v = *(const float4*)(win + t * 4);
    red[t] = v.x * v.x + v.y * v.y + v.z * v.z + v.w * v.w;
    __syncthreads();
    for (int o = 128; o > 0; o >>= 1) {
        if (t < o) red[t] += red[t + o];
        __syncthreads();
    }
    float inv = 1.f / (sqrtf(red[0]) + 1e-12f);
    int row = blockIdx.x * 4 + (t >> 6);
    int lane = t & 63;
    const float* hr = H + (size_t)row * 1024;
    float s = 0.f;
#pragma unroll
    for (int seg = 0; seg < 4; ++seg) {
        float4 hv = *(const float4*)(hr + seg * 256 + lane * 4);
        float4 uv = *(const float4*)(win + seg * 256 + lane * 4);
        s += hv.x * uv.x + hv.y * uv.y + hv.z * uv.z + hv.w * uv.w;
    }
#pragma unroll
    for (int k = 1; k < 64; k <<= 1) s += __shfl_xor(s, k);
    if (lane == 0) wout[row] = s * inv;
}

// eta = 1.8*(w9.w10) / ((||w9||+1e-12) * (w10.w10))
__global__ __launch_bounds__(256) void k_eta3(const float* __restrict__ w9,
                                              const float* __restrict__ w10,
                                              float* __restrict__ eta) {
    __shared__ float r99[256], r910[256], r1010[256];
    int t = threadIdx.x;
    float4 a = *(const float4*)(w9 + t * 4);
    float4 b = *(const float4*)(w10 + t * 4);
    r99[t] = a.x * a.x + a.y * a.y + a.z * a.z + a.w * a.w;
    r910[t] = a.x * b.x + a.y * b.y + a.z * b.z + a.w * b.w;
    r1010[t] = b.x * b.x + b.y * b.y + b.z * b.z + b.w * b.w;
    __syncthreads();
    for (int o = 128; o > 0; o >>= 1) {
        if (t < o) {
            r99[t] += r99[t + o];
            r910[t] += r910[t + o];
            r1010[t] += r1010[t + o];
        }
        __syncthreads();
    }
    if (t == 0)
        eta[0] = 1.8f * r910[0] / ((sqrtf(r99[0]) + 1e-12f) * r1010[0]);
}

// ---------------- fp16x2 split NT MFMA GEMM (32x32x16) ----------------
// C[i][j] = sum_k Aop[i][k]*Bop[j][k]. Block 128x128, 4 waves (2x2), each
// wave 64x64 (2x2 frags of 32x32). BK=32, double-buffered LDS (64KB),
// raw-barrier loop with counted vmcnt(8) (next tile's 8 global_load_lds
// remain in flight across the barrier). 2 blocks/CU.
// LDS tile row = 8 x 16B slots: slots 0-3 = hi k-chunks, 4-7 = lo k-chunks,
// physical slot = logical ^ (row&7) (involution; staged via swizzled source).
// EPI 0: fout = acc                          (H)
// EPI 1: rv = eta*(acc - b[j]) -> fout; lam0 = relu(rv) split
// EPI 2: lam = relu(acc + raux) split        (iteration)
// EPI 3: fout = raux - acc                   (final out; raux = x)

template <int EPI>
__global__ __launch_bounds__(256, 2) void k_mm3(
    const _Float16* __restrict__ Agh, const _Float16* __restrict__ Agl,
    const _Float16* __restrict__ Bgh, const _Float16* __restrict__ Bgl,
    int Kd, int Nd,
    const float* __restrict__ eta_p, const float* __restrict__ bvec,
    const float* __restrict__ raux, float* __restrict__ fout,
    _Float16* __restrict__ lamh, _Float16* __restrict__ laml) {
    __shared__ __align__(16) char lds[65536];

    const int t = threadIdx.x;
    const int wid = t >> 6, lane = t & 63;
    const int wr = wid >> 1, wc = wid & 1;
    const int l31 = lane & 31, g2 = lane >> 5;

    // chunked bijective XCD swizzle: XCD k owns a (gx/8) x gy sub-grid.
    // requires gridDim.x % 8 == 0 (true: 32 or 8) and dispatch id%8 -> XCD.
    const int gx = gridDim.x, gy = gridDim.y;
    const int id = blockIdx.x + blockIdx.y * gx;
    const int xcd = id & 7, q = id >> 3;
    const int rowBlk = xcd * (gx >> 3) + q / gy;
    const int colBlk = q % gy;
    const int rowBase = rowBlk * 128;
    const int colBase = colBlk * 128;

    // staging source (pre-swizzled so linear LDS dest holds swizzled layout)
    const int srow = t >> 3;                 // 0..31: row within 32-row group
    const int slot = t & 7;                  // 16B slot within row
    const int jch = slot ^ (srow & 7);       // logical chunk at this slot
    const int kch = (jch & 3) * 8;           // k element offset (per h/l half)
    const _Float16* srcA =
        (jch >= 4 ? Agl : Agh) + (size_t)(rowBase + srow) * Kd + kch;
    const _Float16* srcB =
        (jch >= 4 ? Bgl : Bgh) + (size_t)(colBase + srow) * Kd + kch;
    const size_t qStep = (size_t)32 * Kd;

    // 8 global_load_lds per thread per STAGE (4 A + 4 B)
#define STAGE(P, KO)                                                         \
    {                                                                        \
        _Pragma("unroll") for (int qq = 0; qq < 4; ++qq)                     \
            GLD16(srcA + (KO) + qq * qStep,                                  \
                  lds + (P)*32768 + qq * 4096 + wid * 1024);                 \
        _Pragma("unroll") for (int qq = 0; qq < 4; ++qq)                     \
            GLD16(srcB + (KO) + qq * qStep,                                  \
                  lds + (P)*32768 + 16384 + qq * 4096 + wid * 1024);         \
    }

    f32x16 acch[2][2], accm[2][2];
#pragma unroll
    for (int m2 = 0; m2 < 2; ++m2)
#pragma unroll
        for (int n2 = 0; n2 < 2; ++n2) {
            acch[m2][n2] = (f32x16)0.f;
            accm[m2][n2] = (f32x16)0.f;
        }

    STAGE(0, 0);  // 8 loads in flight

    const int NS = Kd >> 5;
    for (int ks = 0; ks < NS; ++ks) {
        const int p = ks & 1;
        if (ks + 1 < NS) {
            STAGE(p ^ 1, (ks + 1) << 5);  // 16 in flight
            // wait only for the OLDEST 8 (buffer p); new 8 stay in flight
            asm volatile("s_waitcnt vmcnt(8)" ::: "memory");
        } else {
            asm volatile("s_waitcnt vmcnt(0)" ::: "memory");
        }
        asm volatile("s_barrier" ::: "memory");  // all waves: buf p ready

        const char* base = lds + p * 32768;
#pragma unroll
        for (int ksub = 0; ksub < 2; ++ksub) {
            const int j = ksub * 2 + g2;
            f16x8 ah[2], al[2], bh[2], bl[2];
#pragma unroll
            for (int m2 = 0; m2 < 2; ++m2) {
                int row = wr * 64 + m2 * 32 + l31;
                const char* rp = base + row * 128;
                ah[m2] = *(const f16x8*)(rp + ((j ^ (row & 7)) << 4));
                al[m2] = *(const f16x8*)(rp + (((j + 4) ^ (row & 7)) << 4));
            }
#pragma unroll
            for (int n2 = 0; n2 < 2; ++n2) {
                int row = wc * 64 + n2 * 32 + l31;
                const char* rp = base + 16384 + row * 128;
                bh[n2] = *(const f16x8*)(rp + ((j ^ (row & 7)) << 4));
                bl[n2] = *(const f16x8*)(rp + (((j + 4) ^ (row & 7)) << 4));
            }
#pragma unroll
            for (int m2 = 0; m2 < 2; ++m2)
#pragma unroll
                for (int n2 = 0; n2 < 2; ++n2) {
                    acch[m2][n2] = __builtin_amdgcn_mfma_f32_32x32x16_f16(
                        ah[m2], bh[n2], acch[m2][n2], 0, 0, 0);
                    accm[m2][n2] = __builtin_amdgcn_mfma_f32_32x32x16_f16(
                        ah[m2], bl[n2], accm[m2][n2], 0, 0, 0);
                    accm[m2][n2] = __builtin_amdgcn_mfma_f32_32x32x16_f16(
                        al[m2], bh[n2], accm[m2][n2], 0, 0, 0);
                }
        }
        // protect buf p from being overwritten by next iteration's STAGE
        // (ds_read results are already consumed by the MFMAs above)
        asm volatile("s_barrier" ::: "memory");
    }
#undef STAGE

    // ---- epilogue; C layout: col = lane&31, row = (reg&3)+8*(reg>>2)+4*g2
    float etav = (EPI == 1) ? eta_p[0] : 0.f;
#pragma unroll
    for (int m2 = 0; m2 < 2; ++m2)
#pragma unroll
        for (int n2 = 0; n2 < 2; ++n2) {
            const int col = colBase + wc * 64 + n2 * 32 + l31;
#pragma unroll
            for (int reg = 0; reg < 16; ++reg) {
                const int row = rowBase + wr * 64 + m2 * 32 + (reg & 3) +
                                ((reg >> 2) << 3) + (g2 << 2);
                const size_t idx = (size_t)row * Nd + col;
                float val =
                    acch[m2][n2][reg] + accm[m2][n2][reg] * 4.8828125e-4f;
                if (EPI == 0) {
                    fout[idx] = val;
                } else if (EPI == 1) {
                    float rv = etav * (val - bvec[col]);
                    fout[idx] = rv;
                    float lv = fmaxf(rv, 0.f);
                    _Float16 h = (_Float16)lv;
                    lamh[idx] = h;
                    laml[idx] = (_Float16)((lv - (float)h) * 2048.f);
                } else if (EPI == 2) {
                    float lv = fmaxf(val + raux[idx], 0.f);
                    _Float16 h = (_Float16)lv;
                    lamh[idx] = h;
                    laml[idx] = (_Float16)((lv - (float)h) * 2048.f);
                } else {
                    fout[idx] = raux[idx] - val;
                }
            }
        }
}

// ---------------------------------------------------------------------------

extern "C" void kernel_launch(void* const* d_in, const int* in_sizes, int n_in,
                              void* d_out, int out_size, void* d_ws, size_t ws_size,
                              hipStream_t stream) {
    const float* x = (const float*)d_in[0];  // [B, d] = [4096, 1024]
    const float* A = (const float*)d_in[1];  // [m, d] = [1024, 1024]
    const float* b = (const float*)d_in[2];  // [m]

    const int m = in_sizes[2];           // 1024
    const int dd = in_sizes[1] / m;      // 1024
    const int Bn = in_sizes[0] / dd;     // 4096
    float* out = (float*)d_out;

    // workspace layout (<= 60 MB + 16 KB; x-split region is reused as l1,
    // H region is reused for A^T split after the iterations)
    const size_t MB = 1u << 20;
    char* w8 = (char*)d_ws;
    float* eta = (float*)w8;                       // 256 B
    float* wA = (float*)(w8 + 256);                // 4 KB
    float* wB = (float*)(w8 + 256 + 4096);         // 4 KB
    char* base = w8 + 16384;
    float* H = (float*)base;                       // 4 MB (later: AT split)
    _Float16* ATh = (_Float16*)base;               //   2 MB (aliases H)
    _Float16* ATl = (_Float16*)(base + 2 * MB);    //   2 MB (aliases H)
    _Float16* Mh = (_Float16*)(base + 4 * MB);     // 2 MB
    _Float16* Ml = (_Float16*)(base + 6 * MB);     // 2 MB
    _Float16* Ah = (_Float16*)(base + 8 * MB);     // 2 MB
    _Float16* Al = (_Float16*)(base + 10 * MB);    // 2 MB
    _Float16* xh = (_Float16*)(base + 12 * MB);    // 8 MB (later: l1h)
    _Float16* xl = (_Float16*)(base + 20 * MB);    // 8 MB (later: l1l)
    float* r = (float*)(base + 28 * MB);           // 16 MB
    _Float16* l0h = (_Float16*)(base + 44 * MB);   // 8 MB
    _Float16* l0l = (_Float16*)(base + 52 * MB);   // 8 MB
    _Float16* l1h = xh;
    _Float16* l1l = xl;

    // ---- split A and x ----
    k_split<<<(m * dd) / 1024, 256, 0, stream>>>(A, Ah, Al);
    k_split<<<(Bn * dd) / 1024, 256, 0, stream>>>(x, xh, xl);

    // ---- H = A A^T ----
    k_mm3<0><<<dim3(m / 128, m / 128), 256, 0, stream>>>(
        Ah, Al, Ah, Al, dd, m, nullptr, nullptr, nullptr, H, nullptr, nullptr);

    // ---- power iteration: eta = 1.8/lambda_max(H) ----
    k_u0<<<m / 16, 256, 0, stream>>>(A, wA);
    for (int it = 0; it < 5; ++it) {
        k_pmv<<<m / 4, 256, 0, stream>>>(H, wA, wB);
        k_pmv<<<m / 4, 256, 0, stream>>>(H, wB, wA);
    }
    // w9 in wB, w10 in wA
    k_eta3<<<1, 256, 0, stream>>>(wB, wA, eta);

    // ---- M = I - eta*H (split f16) ----
    k_makeM<<<(m * m) / 1024, 256, 0, stream>>>(H, eta, Mh, Ml);

    // ---- r = eta*(x A^T - b); lam0 = relu(r) split ----
    k_mm3<1><<<dim3(Bn / 128, m / 128), 256, 0, stream>>>(
        xh, xl, Ah, Al, dd, m, eta, b, nullptr, r, l0h, l0l);

    // ---- 29 iterations: lam <- relu(lam M + r) ----
    const _Float16 *pih = l0h, *pil = l0l;
    _Float16 *poh = l1h, *pol = l1l;
    for (int it = 0; it < 29; ++it) {
        k_mm3<2><<<dim3(Bn / 128, m / 128), 256, 0, stream>>>(
            pih, pil, Mh, Ml, m, m, nullptr, nullptr, r, nullptr, poh, pol);
        const _Float16* th = pih;
        const _Float16* tl = pil;
        pih = poh; pil = pol;
        poh = (_Float16*)th; pol = (_Float16*)tl;
    }
    // 29 steps: final lam in l1 (x-split no longer needed)

    // ---- A^T split into old H region; out = x - lam A ----
    k_tsplit<<<dim3(m / 32, dd / 32), 256, 0, stream>>>(A, ATh, ATl);
    k_mm3<3><<<dim3(Bn / 128, dd / 128), 256, 0, stream>>>(
        pih, pil, ATh, ATl, m, dd, nullptr, nullptr, x, out, nullptr, nullptr);
}